// Round 18
// baseline (129.535 us; speedup 1.0000x reference)
//
#include <hip/hip_runtime.h>
#include <hip/hip_bf16.h>

#define L_SEQ    1024
#define IN_DIM   256
#define DIM_MSA  32
#define PAIR_DIM 64

typedef float f4 __attribute__((ext_vector_type(4)));
typedef short s8 __attribute__((ext_vector_type(8)));

__device__ __forceinline__ unsigned short f2bf(float f) {
    unsigned u = __float_as_uint(f);
    u = (u + 0x7FFFu + ((u >> 16) & 1u)) >> 16;   // RNE
    return (unsigned short)u;
}

// s[i][c] = b1[c] + sum_d seq[i][d] * W1[c][d]  (fp32 + bf16 copies)
__global__ void k_proj1(const float* __restrict__ seq, const float* __restrict__ W1,
                        const float* __restrict__ b1, float* __restrict__ s,
                        unsigned short* __restrict__ s_bf) {
    int t = blockIdx.x * blockDim.x + threadIdx.x;   // 1024*32 threads
    int i = t >> 5, c = t & 31;
    const float4* sq = (const float4*)(seq + i * IN_DIM);
    const float4* w  = (const float4*)(W1  + c * IN_DIM);
    float a0 = 0.f, a1 = 0.f, a2 = 0.f, a3 = 0.f;
#pragma unroll
    for (int d4 = 0; d4 < IN_DIM / 4; ++d4) {
        float4 x = sq[d4], y = w[d4];
        a0 += x.x * y.x;  a1 += x.y * y.y;
        a2 += x.z * y.z;  a3 += x.w * y.w;
    }
    float v = b1[c] + ((a0 + a1) + (a2 + a3));
    s[t]    = v;
    s_bf[t] = f2bf(v);
}

// tmp_bf[jp][d] = bf16( sum_c s[j][c] * W2[p][c*32+d] ), jp = j*64+p
__global__ void k_proj2(const float* __restrict__ s, const float* __restrict__ W2,
                        unsigned short* __restrict__ tmp_bf) {
    int t = blockIdx.x * blockDim.x + threadIdx.x;   // 1024*64*8 threads
    int q = t & 7, p = (t >> 3) & 63, j = t >> 9;
    const float4* w  = (const float4*)W2;            // idx = p*256 + c*8 + q
    const float*  sj = s + j * DIM_MSA;
    float4 acc = {0.f, 0.f, 0.f, 0.f};
#pragma unroll
    for (int c = 0; c < DIM_MSA; ++c) {
        float  sc = sj[c];
        float4 wv = w[p * 256 + c * 8 + q];
        acc.x += sc * wv.x;  acc.y += sc * wv.y;
        acc.z += sc * wv.z;  acc.w += sc * wv.w;
    }
    ushort4 o;
    o.x = f2bf(acc.x);  o.y = f2bf(acc.y);
    o.z = f2bf(acc.z);  o.w = f2bf(acc.w);
    ((ushort4*)tmp_bf)[t] = o;   // shorts 4t..4t+3 == [jp][d] row-major
}

// out[i][jp] = MFMA(s_bf, tmp_bf) + b2 + pair; LDS-transposed epilogue.
// R14 structure exactly (16 MFMA tiles, 16KB wave slab, f4 1KB/instr streams)
// with ONE change: PLAIN stores (write-allocate) instead of nt stores.
// Theory: fillBuffer (plain stores) hits 7 TB/s via MALL write buffering;
// nt stores bypass the MALL and contend with the read stream at DRAM.
// A/B diagnostic: FETCH_SIZE will rise (out evicts some pair from L3);
// net dur decides which effect dominates.
__global__ __launch_bounds__(256) void k_outer_mfma5(
    const unsigned short* __restrict__ s_bf, const unsigned short* __restrict__ tmp_bf,
    const float* __restrict__ pair, const float* __restrict__ b2,
    float* __restrict__ out) {
    __shared__ float lds[4 * 16 * 256];          // 64 KB
    int tid = threadIdx.x;
    int w = tid >> 6, l = tid & 63;
    int n = l & 15, kg = l >> 4;
    int jb = blockIdx.x & 63;                    // jp-block fast axis
    int it = blockIdx.x >> 6;                    // i-tile

    // A-frag: s_bf[it*16 + n][kg*8 .. +7]
    s8 a = *(const s8*)(s_bf + (size_t)(it * 16 + n) * DIM_MSA + kg * 8);

    int jp0 = jb * 1024 + w * 256;               // wave's jp range
    const unsigned short* bp = tmp_bf + (size_t)(jp0 + n) * DIM_MSA + kg * 8;
    float* myl = lds + w * 4096;                 // wave-private 16 KB

    // ---- phase 1: 16 MFMA tiles -> LDS [16 i][256 jp] ----
#pragma unroll
    for (int t = 0; t < 16; ++t) {
        s8 b = *(const s8*)(bp + (size_t)t * 16 * DIM_MSA);  // 1KB/wave, L2
        f4 z = {0.f, 0.f, 0.f, 0.f};
        f4 c = __builtin_amdgcn_mfma_f32_16x16x32_bf16(a, b, z, 0, 0, 0);
        // C: reg r -> i_loc = kg*4 + r, jp_loc = t*16 + n
        float* dst = myl + (kg * 4) * 256 + t * 16 + n;
        dst[0]   = c.x;
        dst[256] = c.y;
        dst[512] = c.z;
        dst[768] = c.w;
    }
    // same-wave RAW through LDS: compiler inserts lgkmcnt wait; no barrier.

    // ---- phase 2: stream 16 i-rows (f4 = 1KB/instr per wave) ----
    f4 b4 = *(const f4*)(b2 + ((l * 4) & 63));
    size_t rowbase = (size_t)(it * 16) * 65536 + (size_t)jp0 + l * 4;
    const float* pp = pair + rowbase;
    float*       op = out  + rowbase;

#pragma unroll
    for (int i = 0; i < 16; ++i) {
        f4 cc = *(const f4*)(myl + i * 256 + l * 4);
        f4 pv = *(const f4*)(pp + (size_t)i * 65536);
        *(f4*)(op + (size_t)i * 65536) = cc + b4 + pv;      // plain store
    }
}

extern "C" void kernel_launch(void* const* d_in, const int* in_sizes, int n_in,
                              void* d_out, int out_size, void* d_ws, size_t ws_size,
                              hipStream_t stream) {
    const float* seq  = (const float*)d_in[0];   // [1,1024,256]
    const float* pair = (const float*)d_in[1];   // [1,1024,1024,64]
    const float* W1   = (const float*)d_in[2];   // [32,256]
    const float* b1   = (const float*)d_in[3];   // [32]
    const float* W2   = (const float*)d_in[4];   // [64,1024]
    const float* b2   = (const float*)d_in[5];   // [64]
    float* out = (float*)d_out;

    float*          s_ws = (float*)d_ws;                     // 128 KB fp32
    unsigned short* sbf  = (unsigned short*)(s_ws + 32768);  // 64 KB bf16
    unsigned short* tbf  = sbf + 32768;                      // 4 MB bf16 [jp][d]

    k_proj1<<<(L_SEQ * DIM_MSA) / 256, 256, 0, stream>>>(seq, W1, b1, s_ws, sbf);
    k_proj2<<<(L_SEQ * PAIR_DIM * (DIM_MSA / 4)) / 256, 256, 0, stream>>>(s_ws, W2, tbf);
    k_outer_mfma5<<<64 * 64, 256, 0, stream>>>(sbf, tbf, pair, b2, out);
}

// Round 19
// 121.151 us; speedup vs baseline: 1.0692x; 1.0692x over previous
//
#include <hip/hip_runtime.h>
#include <hip/hip_bf16.h>

#define L_SEQ    1024
#define IN_DIM   256
#define DIM_MSA  32
#define PAIR_DIM 64

typedef float f4 __attribute__((ext_vector_type(4)));
typedef short s8 __attribute__((ext_vector_type(8)));

__device__ __forceinline__ unsigned short f2bf(float f) {
    unsigned u = __float_as_uint(f);
    u = (u + 0x7FFFu + ((u >> 16) & 1u)) >> 16;   // RNE
    return (unsigned short)u;
}

// s[i][c] = b1[c] + sum_d seq[i][d] * W1[c][d]  (fp32 + bf16 copies)
__global__ void k_proj1(const float* __restrict__ seq, const float* __restrict__ W1,
                        const float* __restrict__ b1, float* __restrict__ s,
                        unsigned short* __restrict__ s_bf) {
    int t = blockIdx.x * blockDim.x + threadIdx.x;   // 1024*32 threads
    int i = t >> 5, c = t & 31;
    const float4* sq = (const float4*)(seq + i * IN_DIM);
    const float4* w  = (const float4*)(W1  + c * IN_DIM);
    float a0 = 0.f, a1 = 0.f, a2 = 0.f, a3 = 0.f;
#pragma unroll
    for (int d4 = 0; d4 < IN_DIM / 4; ++d4) {
        float4 x = sq[d4], y = w[d4];
        a0 += x.x * y.x;  a1 += x.y * y.y;
        a2 += x.z * y.z;  a3 += x.w * y.w;
    }
    float v = b1[c] + ((a0 + a1) + (a2 + a3));
    s[t]    = v;
    s_bf[t] = f2bf(v);
}

// tmp_bf[jp][d] = bf16( sum_c s[j][c] * W2[p][c*32+d] ), jp = j*64+p
__global__ void k_proj2(const float* __restrict__ s, const float* __restrict__ W2,
                        unsigned short* __restrict__ tmp_bf) {
    int t = blockIdx.x * blockDim.x + threadIdx.x;   // 1024*64*8 threads
    int q = t & 7, p = (t >> 3) & 63, j = t >> 9;
    const float4* w  = (const float4*)W2;            // idx = p*256 + c*8 + q
    const float*  sj = s + j * DIM_MSA;
    float4 acc = {0.f, 0.f, 0.f, 0.f};
#pragma unroll
    for (int c = 0; c < DIM_MSA; ++c) {
        float  sc = sj[c];
        float4 wv = w[p * 256 + c * 8 + q];
        acc.x += sc * wv.x;  acc.y += sc * wv.y;
        acc.z += sc * wv.z;  acc.w += sc * wv.w;
    }
    ushort4 o;
    o.x = f2bf(acc.x);  o.y = f2bf(acc.y);
    o.z = f2bf(acc.z);  o.w = f2bf(acc.w);
    ((ushort4*)tmp_bf)[t] = o;   // shorts 4t..4t+3 == [jp][d] row-major
}

// out[i][jp] = MFMA(s_bf, tmp_bf) + b2 + pair; LDS-transposed epilogue.
// TWO work-items per block: (it, jb) and (it, jb+32) — same A-frag.
// Software pipeline: item1's 16 B-tile loads are ISSUED before item0's
// streaming phase, so their L2/HBM latency lands under 32 streaming VMEM ops;
// item1's MFMA phase then runs stall-free. Steady-state serial (non-stream)
// cost per item = MFMA + LDS ops only. Structure otherwise R14 (16 KB wave
// slab, f4 1KB/instr streams, nt stores). launch_bounds(256,2): VGPR budget
// for the 16-entry b-frag array (compile-time indices only).
__global__ __launch_bounds__(256, 2) void k_outer_mfma7(
    const unsigned short* __restrict__ s_bf, const unsigned short* __restrict__ tmp_bf,
    const float* __restrict__ pair, const float* __restrict__ b2,
    float* __restrict__ out) {
    __shared__ float lds[4 * 16 * 256];          // 64 KB
    int tid = threadIdx.x;
    int w = tid >> 6, l = tid & 63;
    int n = l & 15, kg = l >> 4;
    int jb0 = blockIdx.x & 31;                   // item0 j-block
    int it  = blockIdx.x >> 5;                   // i-tile
    int jb1 = jb0 + 32;                          // item1 j-block

    // A-frag: s_bf[it*16 + n][kg*8 .. +7]  (shared by both items)
    s8 a = *(const s8*)(s_bf + (size_t)(it * 16 + n) * DIM_MSA + kg * 8);
    float* myl = lds + w * 4096;                 // wave-private 16 KB
    f4 b4 = *(const f4*)(b2 + ((l * 4) & 63));

    int jp0 = jb0 * 1024 + w * 256;
    int jp1 = jb1 * 1024 + w * 256;
    const unsigned short* bp0 = tmp_bf + (size_t)(jp0 + n) * DIM_MSA + kg * 8;
    const unsigned short* bp1 = tmp_bf + (size_t)(jp1 + n) * DIM_MSA + kg * 8;
    size_t rb0 = (size_t)(it * 16) * 65536 + (size_t)jp0 + l * 4;
    size_t rb1 = (size_t)(it * 16) * 65536 + (size_t)jp1 + l * 4;

    s8 b[16];
    // ---- B loads item0 ----
#pragma unroll
    for (int t = 0; t < 16; ++t)
        b[t] = *(const s8*)(bp0 + (size_t)t * 512);
    // ---- MFMA item0 -> slab ----
#pragma unroll
    for (int t = 0; t < 16; ++t) {
        f4 z = {0.f, 0.f, 0.f, 0.f};
        f4 c = __builtin_amdgcn_mfma_f32_16x16x32_bf16(a, b[t], z, 0, 0, 0);
        float* dst = myl + (kg * 4) * 256 + t * 16 + n;   // i_loc=kg*4+r, jp_loc=t*16+n
        dst[0]   = c.x;
        dst[256] = c.y;
        dst[512] = c.z;
        dst[768] = c.w;
    }
    // ---- issue B loads item1 (latency hides under item0 streaming) ----
#pragma unroll
    for (int t = 0; t < 16; ++t)
        b[t] = *(const s8*)(bp1 + (size_t)t * 512);

    // ---- stream item0 (16 x f4 pair load + nt store, 1KB/instr) ----
    {
        const float* pp = pair + rb0;
        float*       op = out  + rb0;
#pragma unroll
        for (int i = 0; i < 16; ++i) {
            f4 cc = *(const f4*)(myl + i * 256 + l * 4);
            f4 pv = *(const f4*)(pp + (size_t)i * 65536);
            __builtin_nontemporal_store(cc + b4 + pv, (f4*)(op + (size_t)i * 65536));
        }
    }
    // ---- MFMA item1 -> slab (B data already landed) ----
#pragma unroll
    for (int t = 0; t < 16; ++t) {
        f4 z = {0.f, 0.f, 0.f, 0.f};
        f4 c = __builtin_amdgcn_mfma_f32_16x16x32_bf16(a, b[t], z, 0, 0, 0);
        float* dst = myl + (kg * 4) * 256 + t * 16 + n;
        dst[0]   = c.x;
        dst[256] = c.y;
        dst[512] = c.z;
        dst[768] = c.w;
    }
    // ---- stream item1 ----
    {
        const float* pp = pair + rb1;
        float*       op = out  + rb1;
#pragma unroll
        for (int i = 0; i < 16; ++i) {
            f4 cc = *(const f4*)(myl + i * 256 + l * 4);
            f4 pv = *(const f4*)(pp + (size_t)i * 65536);
            __builtin_nontemporal_store(cc + b4 + pv, (f4*)(op + (size_t)i * 65536));
        }
    }
}

extern "C" void kernel_launch(void* const* d_in, const int* in_sizes, int n_in,
                              void* d_out, int out_size, void* d_ws, size_t ws_size,
                              hipStream_t stream) {
    const float* seq  = (const float*)d_in[0];   // [1,1024,256]
    const float* pair = (const float*)d_in[1];   // [1,1024,1024,64]
    const float* W1   = (const float*)d_in[2];   // [32,256]
    const float* b1   = (const float*)d_in[3];   // [32]
    const float* W2   = (const float*)d_in[4];   // [64,1024]
    const float* b2   = (const float*)d_in[5];   // [64]
    float* out = (float*)d_out;

    float*          s_ws = (float*)d_ws;                     // 128 KB fp32
    unsigned short* sbf  = (unsigned short*)(s_ws + 32768);  // 64 KB bf16
    unsigned short* tbf  = sbf + 32768;                      // 4 MB bf16 [jp][d]

    k_proj1<<<(L_SEQ * DIM_MSA) / 256, 256, 0, stream>>>(seq, W1, b1, s_ws, sbf);
    k_proj2<<<(L_SEQ * PAIR_DIM * (DIM_MSA / 4)) / 256, 256, 0, stream>>>(s_ws, W2, tbf);
    k_outer_mfma7<<<64 * 32, 256, 0, stream>>>(sbf, tbf, pair, b2, out);
}

// Round 20
// 112.590 us; speedup vs baseline: 1.1505x; 1.0760x over previous
//
#include <hip/hip_runtime.h>
#include <hip/hip_bf16.h>

#define L_SEQ    1024
#define IN_DIM   256
#define DIM_MSA  32
#define PAIR_DIM 64

typedef float f4 __attribute__((ext_vector_type(4)));
typedef short s8 __attribute__((ext_vector_type(8)));

__device__ __forceinline__ unsigned short f2bf(float f) {
    unsigned u = __float_as_uint(f);
    u = (u + 0x7FFFu + ((u >> 16) & 1u)) >> 16;   // RNE
    return (unsigned short)u;
}

// s[i][c] = b1[c] + sum_d seq[i][d] * W1[c][d]  (fp32 + bf16 copies)
__global__ void k_proj1(const float* __restrict__ seq, const float* __restrict__ W1,
                        const float* __restrict__ b1, float* __restrict__ s,
                        unsigned short* __restrict__ s_bf) {
    int t = blockIdx.x * blockDim.x + threadIdx.x;   // 1024*32 threads
    int i = t >> 5, c = t & 31;
    const float4* sq = (const float4*)(seq + i * IN_DIM);
    const float4* w  = (const float4*)(W1  + c * IN_DIM);
    float a0 = 0.f, a1 = 0.f, a2 = 0.f, a3 = 0.f;
#pragma unroll
    for (int d4 = 0; d4 < IN_DIM / 4; ++d4) {
        float4 x = sq[d4], y = w[d4];
        a0 += x.x * y.x;  a1 += x.y * y.y;
        a2 += x.z * y.z;  a3 += x.w * y.w;
    }
    float v = b1[c] + ((a0 + a1) + (a2 + a3));
    s[t]    = v;
    s_bf[t] = f2bf(v);
}

// tmp_bf[jp][d] = bf16( sum_c s[j][c] * W2[p][c*32+d] ), jp = j*64+p
__global__ void k_proj2(const float* __restrict__ s, const float* __restrict__ W2,
                        unsigned short* __restrict__ tmp_bf) {
    int t = blockIdx.x * blockDim.x + threadIdx.x;   // 1024*64*8 threads
    int q = t & 7, p = (t >> 3) & 63, j = t >> 9;
    const float4* w  = (const float4*)W2;            // idx = p*256 + c*8 + q
    const float*  sj = s + j * DIM_MSA;
    float4 acc = {0.f, 0.f, 0.f, 0.f};
#pragma unroll
    for (int c = 0; c < DIM_MSA; ++c) {
        float  sc = sj[c];
        float4 wv = w[p * 256 + c * 8 + q];
        acc.x += sc * wv.x;  acc.y += sc * wv.y;
        acc.z += sc * wv.z;  acc.w += sc * wv.w;
    }
    ushort4 o;
    o.x = f2bf(acc.x);  o.y = f2bf(acc.y);
    o.z = f2bf(acc.z);  o.w = f2bf(acc.w);
    ((ushort4*)tmp_bf)[t] = o;   // shorts 4t..4t+3 == [jp][d] row-major
}

// out[i][jp] = MFMA(tmp_bf, s_bf) + b2 + pair; LDS-transposed epilogue.
// R14 with OPERANDS SWAPPED: A = tmp tile (M=jp), B = s frag (N=i).
// C then gives each lane 4 CONSECUTIVE jp at fixed i -> phase-1 LDS writes
// become 16 ds_write_b128 (was 64 ds_write_b32). XOR swizzle ((n&7)<<2)
// spreads banks; phase-2 b128 reads unswizzle with the same XOR.
// Everything else identical to R14 (nt stores, plain pair loads -> keep
// cross-replay L3 hits, 16KB wave slab, f4 1KB/instr streams).
__global__ __launch_bounds__(256) void k_outer_mfma8(
    const unsigned short* __restrict__ s_bf, const unsigned short* __restrict__ tmp_bf,
    const float* __restrict__ pair, const float* __restrict__ b2,
    float* __restrict__ out) {
    __shared__ float lds[4 * 16 * 256];          // 64 KB
    int tid = threadIdx.x;
    int w = tid >> 6, l = tid & 63;
    int n = l & 15, kg = l >> 4;
    int jb = blockIdx.x & 63;                    // jp-block fast axis
    int it = blockIdx.x >> 6;                    // i-tile

    // B-frag (N = i): s_bf[it*16 + n][kg*8 .. +7]
    s8 bs = *(const s8*)(s_bf + (size_t)(it * 16 + n) * DIM_MSA + kg * 8);

    int jp0 = jb * 1024 + w * 256;               // wave's jp range
    const unsigned short* ap = tmp_bf + (size_t)(jp0 + n) * DIM_MSA + kg * 8;
    float* myl = lds + w * 4096;                 // wave-private 16 KB

    // ---- phase 1: 16 MFMA tiles -> LDS [16 i][256 jp] via b128 writes ----
#pragma unroll
    for (int t = 0; t < 16; ++t) {
        s8 at = *(const s8*)(ap + (size_t)t * 16 * DIM_MSA);  // 1KB/wave, L2
        f4 z = {0.f, 0.f, 0.f, 0.f};
        f4 c = __builtin_amdgcn_mfma_f32_16x16x32_bf16(at, bs, z, 0, 0, 0);
        // C: col = i = n, rows = jp_loc = t*16 + kg*4 + (0..3)  -> one b128
        int col = (t * 16 + kg * 4) ^ ((n & 7) << 2);         // swizzled
        *(f4*)(myl + n * 256 + col) = c;
    }
    // same-wave RAW through LDS: compiler inserts lgkmcnt wait; no barrier.

    // ---- phase 2: stream 16 i-rows (f4 = 1KB/instr per wave) ----
    f4 b4 = *(const f4*)(b2 + ((l * 4) & 63));
    size_t rowbase = (size_t)(it * 16) * 65536 + (size_t)jp0 + l * 4;
    const float* pp = pair + rowbase;
    float*       op = out  + rowbase;

#pragma unroll 8
    for (int i = 0; i < 16; ++i) {
        int col = (l * 4) ^ ((i & 7) << 2);                   // unswizzle
        f4 cc = *(const f4*)(myl + i * 256 + col);
        f4 pv = *(const f4*)(pp + (size_t)i * 65536);
        __builtin_nontemporal_store(cc + b4 + pv, (f4*)(op + (size_t)i * 65536));
    }
}

extern "C" void kernel_launch(void* const* d_in, const int* in_sizes, int n_in,
                              void* d_out, int out_size, void* d_ws, size_t ws_size,
                              hipStream_t stream) {
    const float* seq  = (const float*)d_in[0];   // [1,1024,256]
    const float* pair = (const float*)d_in[1];   // [1,1024,1024,64]
    const float* W1   = (const float*)d_in[2];   // [32,256]
    const float* b1   = (const float*)d_in[3];   // [32]
    const float* W2   = (const float*)d_in[4];   // [64,1024]
    const float* b2   = (const float*)d_in[5];   // [64]
    float* out = (float*)d_out;

    float*          s_ws = (float*)d_ws;                     // 128 KB fp32
    unsigned short* sbf  = (unsigned short*)(s_ws + 32768);  // 64 KB bf16
    unsigned short* tbf  = sbf + 32768;                      // 4 MB bf16 [jp][d]

    k_proj1<<<(L_SEQ * DIM_MSA) / 256, 256, 0, stream>>>(seq, W1, b1, s_ws, sbf);
    k_proj2<<<(L_SEQ * PAIR_DIM * (DIM_MSA / 4)) / 256, 256, 0, stream>>>(s_ws, W2, tbf);
    k_outer_mfma8<<<64 * 64, 256, 0, stream>>>(sbf, tbf, pair, b2, out);
}